// Round 1
// baseline (1114.143 us; speedup 1.0000x reference)
//
#include <hip/hip_runtime.h>
#include <math.h>

// Problem constants
#define B_  8
#define D_  1024
#define T_  2048
#define CD_ 256
#define CS_ 8192

// ws layout (in floats). Total ~10.6 MB.
#define WS_CBT   0                       // cbT [CD][CS]
#define WS_WINT  (CD_*CS_)               // w_inT [D][CD]
#define WS_WOUTT (WS_WINT + D_*CD_)      // w_outT [CD][D]
#define WS_C2    (WS_WOUTT + CD_*D_)     // c2 [CS]
#define WS_IDX   (WS_C2 + CS_)           // int idx [B*T]

// d_out layout (floats): z_q, indices(as float), z_e
#define OUT_ZQ  0
#define OUT_IDX (B_*D_*T_)
#define OUT_ZE  (OUT_IDX + B_*T_)

__device__ __forceinline__ float wave_sum64(float v) {
#pragma unroll
  for (int off = 32; off >= 1; off >>= 1) v += __shfl_xor(v, off);
  return v;
}

// ---- prep: w_inT[d][c] = in_g[c] * in_v[c][d] / ||in_v[c,:]|| ----
__global__ void prep_win(const float* __restrict__ in_v,
                         const float* __restrict__ in_g,
                         float* __restrict__ w_inT) {
  int c = blockIdx.x, tid = threadIdx.x;  // 256 threads
  float v[4]; float s = 0.f;
#pragma unroll
  for (int i = 0; i < 4; ++i) {
    v[i] = in_v[c * D_ + tid + 256 * i];
    s = fmaf(v[i], v[i], s);
  }
  s = wave_sum64(s);
  __shared__ float sh[4];
  if ((tid & 63) == 0) sh[tid >> 6] = s;
  __syncthreads();
  float tot = sh[0] + sh[1] + sh[2] + sh[3];
  float scale = in_g[c] / sqrtf(tot);
#pragma unroll
  for (int i = 0; i < 4; ++i)
    w_inT[(tid + 256 * i) * CD_ + c] = v[i] * scale;
}

// ---- prep: w_outT[c][d] = out_g[d] * out_v[d][c] / ||out_v[d,:]|| ----
__global__ void prep_wout(const float* __restrict__ out_v,
                          const float* __restrict__ out_g,
                          float* __restrict__ w_outT) {
  int d = blockIdx.x, tid = threadIdx.x;  // 256 threads, c = tid
  float v = out_v[d * CD_ + tid];
  float s = wave_sum64(v * v);
  __shared__ float sh[4];
  if ((tid & 63) == 0) sh[tid >> 6] = s;
  __syncthreads();
  float tot = sh[0] + sh[1] + sh[2] + sh[3];
  float scale = out_g[d] / sqrtf(tot);
  w_outT[tid * D_ + d] = v * scale;
}

// ---- prep: cbT[c][s] = codebook[s][c] (tiled LDS transpose) ----
__global__ void prep_cbt(const float* __restrict__ cb, float* __restrict__ cbT) {
  __shared__ float tile[64 * 65];
  int s0 = blockIdx.x * 64, c0 = blockIdx.y * 64;
  int tid = threadIdx.x;  // 256
#pragma unroll
  for (int i = 0; i < 4; ++i) {
    int lin = tid + 256 * i;
    int sr = lin >> 4, cq = lin & 15;
    float4 v = *(const float4*)&cb[(size_t)(s0 + sr) * CD_ + c0 + cq * 4];
    float* p = &tile[sr * 65 + cq * 4];
    p[0] = v.x; p[1] = v.y; p[2] = v.z; p[3] = v.w;
  }
  __syncthreads();
#pragma unroll
  for (int i = 0; i < 4; ++i) {
    int lin = tid + 256 * i;
    int c = lin >> 4, sq = lin & 15;
    float4 v;
    v.x = tile[(sq * 4 + 0) * 65 + c];
    v.y = tile[(sq * 4 + 1) * 65 + c];
    v.z = tile[(sq * 4 + 2) * 65 + c];
    v.w = tile[(sq * 4 + 3) * 65 + c];
    *(float4*)&cbT[(size_t)(c0 + c) * CS_ + s0 + sq * 4] = v;
  }
}

// ---- prep: c2[s] = sum_c codebook[s][c]^2 ----
__global__ void prep_c2(const float* __restrict__ cb, float* __restrict__ c2) {
  int tid = threadIdx.x;  // 256 = 4 waves, one row per wave
  int w = tid >> 6, lane = tid & 63;
  int s = blockIdx.x * 4 + w;
  float acc = 0.f;
#pragma unroll
  for (int i = 0; i < 4; ++i) {
    float v = cb[(size_t)s * CD_ + lane + 64 * i];
    acc = fmaf(v, v, acc);
  }
  acc = wave_sum64(acc);
  if (lane == 0) c2[s] = acc;
}

// ---- K1: z_e[b][c][t] = sum_d w_in[c][d]*z[b][d][t] + in_b[c] ----
// tile: 64 c-rows x 256 t-cols, TK=32, 512 threads, microtile 8x4
__global__ __launch_bounds__(512) void ze_gemm(
    const float* __restrict__ z, const float* __restrict__ w_inT,
    const float* __restrict__ in_b, float* __restrict__ out) {
  __shared__ __align__(16) float At[32 * 64];
  __shared__ __align__(16) float Bt[32 * 256];
  int tid = threadIdx.x, tx = tid & 63, ty = tid >> 6;
  int t0 = blockIdx.x * 256, c0 = blockIdx.y * 64, b = blockIdx.z;
  const float* zb = z + (size_t)b * D_ * T_;
  float acc[8][4] = {};
  for (int kc = 0; kc < D_; kc += 32) {
    __syncthreads();
    {
      int kk = tid >> 4, rq = tid & 15;
      *(float4*)&At[kk * 64 + rq * 4] =
          *(const float4*)&w_inT[(size_t)(kc + kk) * CD_ + c0 + rq * 4];
    }
    {
      int kk = tid >> 4, tq = tid & 15;
#pragma unroll
      for (int i = 0; i < 4; ++i) {
        int t = tq * 4 + 64 * i;
        *(float4*)&Bt[kk * 256 + t] =
            *(const float4*)&zb[(size_t)(kc + kk) * T_ + t0 + t];
      }
    }
    __syncthreads();
#pragma unroll 8
    for (int kk = 0; kk < 32; ++kk) {
      float a[8], bv[4];
      *(float4*)&a[0] = *(const float4*)&At[kk * 64 + ty * 8];
      *(float4*)&a[4] = *(const float4*)&At[kk * 64 + ty * 8 + 4];
      *(float4*)&bv[0] = *(const float4*)&Bt[kk * 256 + tx * 4];
#pragma unroll
      for (int j = 0; j < 8; ++j)
#pragma unroll
        for (int m = 0; m < 4; ++m)
          acc[j][m] = fmaf(a[j], bv[m], acc[j][m]);
    }
  }
#pragma unroll
  for (int j = 0; j < 8; ++j) {
    int c = c0 + ty * 8 + j;
    float bias = in_b[c];
    float4 o;
    o.x = acc[j][0] + bias; o.y = acc[j][1] + bias;
    o.z = acc[j][2] + bias; o.w = acc[j][3] + bias;
    *(float4*)&out[OUT_ZE + (size_t)(b * CD_ + c) * T_ + t0 + tx * 4] = o;
  }
}

// ---- K2: fused distance + argmin ----
// block: 64 rows (n), all 8192 codes. 512 threads (tx 0..63 codes, ty 0..7 rows)
// microtile 8 rows x 8 codes; At = enc tile [256][64] (full K), Bt = [32][512]
__global__ __launch_bounds__(512) void vq_argmin(
    const float* __restrict__ ze, const float* __restrict__ cbT,
    const float* __restrict__ c2, float* __restrict__ out,
    int* __restrict__ idx_ws) {
  __shared__ __align__(16) float At[CD_ * 64];   // 64 KB
  __shared__ __align__(16) float Bt[32 * 512];   // 64 KB
  float* e2s = Bt;  // aliased: used before first Bt staging, barrier-protected
  int tid = threadIdx.x, tx = tid & 63, ty = tid >> 6;
  int n0 = blockIdx.x * 64;
  int b = n0 >> 11, t0 = n0 & (T_ - 1);
  const float* zeb = ze + (size_t)b * CD_ * T_ + t0;
  // stage full enc tile: At[k][r] = z_e[b][k][t0+r]
#pragma unroll
  for (int i = 0; i < 8; ++i) {
    int lin = tid + 512 * i;
    int k = lin >> 4, rq = lin & 15;
    *(float4*)&At[k * 64 + rq * 4] =
        *(const float4*)&zeb[(size_t)k * T_ + rq * 4];
  }
  __syncthreads();
  if (tid < 64) {
    float s = 0.f;
    for (int k = 0; k < CD_; ++k) {
      float v = At[k * 64 + tid];
      s = fmaf(v, v, s);
    }
    e2s[tid] = s;
  }
  __syncthreads();
  float e2r[8];
#pragma unroll
  for (int j = 0; j < 8; ++j) e2r[j] = e2s[ty * 8 + j];
  float bestv[8]; int besti[8];
#pragma unroll
  for (int j = 0; j < 8; ++j) { bestv[j] = 3.4e38f; besti[j] = 0; }

  for (int s0 = 0; s0 < CS_; s0 += 512) {
    float acc[8][8] = {};
    float c2v[8];
    *(float4*)&c2v[0] = *(const float4*)&c2[s0 + tx * 8];
    *(float4*)&c2v[4] = *(const float4*)&c2[s0 + tx * 8 + 4];
    for (int kc = 0; kc < CD_; kc += 32) {
      __syncthreads();
#pragma unroll
      for (int i = 0; i < 8; ++i) {
        int lin = tid + 512 * i;
        int kk = lin >> 7, cq = lin & 127;
        *(float4*)&Bt[kk * 512 + cq * 4] =
            *(const float4*)&cbT[(size_t)(kc + kk) * CS_ + s0 + cq * 4];
      }
      __syncthreads();
#pragma unroll 4
      for (int kk = 0; kk < 32; ++kk) {
        float a[8], bb[8];
        *(float4*)&a[0] = *(const float4*)&At[(kc + kk) * 64 + ty * 8];
        *(float4*)&a[4] = *(const float4*)&At[(kc + kk) * 64 + ty * 8 + 4];
        *(float4*)&bb[0] = *(const float4*)&Bt[kk * 512 + tx * 8];
        *(float4*)&bb[4] = *(const float4*)&Bt[kk * 512 + tx * 8 + 4];
#pragma unroll
        for (int j = 0; j < 8; ++j)
#pragma unroll
          for (int m = 0; m < 8; ++m)
            acc[j][m] = fmaf(a[j], bb[m], acc[j][m]);
      }
    }
    // dist = (e2 - 2*dot) + c2, same association as numpy; strict < keeps
    // first (smallest-index) minimum like jnp.argmax(-dist).
#pragma unroll
    for (int j = 0; j < 8; ++j)
#pragma unroll
      for (int m = 0; m < 8; ++m) {
        float dv = fmaf(-2.f, acc[j][m], e2r[j]) + c2v[m];
        int ci = s0 + tx * 8 + m;
        if (dv < bestv[j]) { bestv[j] = dv; besti[j] = ci; }
      }
  }
  // per-row reduction across the wave (rows of a wave are ty-uniform)
#pragma unroll
  for (int j = 0; j < 8; ++j) {
    float v = bestv[j]; int bi = besti[j];
#pragma unroll
    for (int off = 32; off >= 1; off >>= 1) {
      float ov = __shfl_xor(v, off);
      int oi = __shfl_xor(bi, off);
      if (ov < v || (ov == v && oi < bi)) { v = ov; bi = oi; }
    }
    bestv[j] = v; besti[j] = bi;
  }
  if (tx == 0) {
#pragma unroll
    for (int j = 0; j < 8; ++j) {
      int n = n0 + ty * 8 + j;
      idx_ws[n] = besti[j];
      out[OUT_IDX + n] = (float)besti[j];
    }
  }
}

// ---- K3: z_q[b][d][t] = sum_c w_out[d][c]*codebook[idx[b][t]][c] + out_b[d]
// tile: 64 d-rows x 256 t-cols, TK=32, 512 threads, microtile 8x4
__global__ __launch_bounds__(512) void zq_gemm(
    const float* __restrict__ cb, const float* __restrict__ w_outT,
    const float* __restrict__ out_bias, const int* __restrict__ idx,
    float* __restrict__ out) {
  __shared__ __align__(16) float At[32 * 64];
  __shared__ __align__(16) float Bt[32 * 256];
  __shared__ int idxs[256];
  int tid = threadIdx.x, tx = tid & 63, ty = tid >> 6;
  int t0 = blockIdx.x * 256, d0 = blockIdx.y * 64, b = blockIdx.z;
  if (tid < 256) idxs[tid] = idx[b * T_ + t0 + tid];
  __syncthreads();
  int t_l = tid & 255, kq = tid >> 8;
  int myidx = idxs[t_l];
  const float* myrow = cb + (size_t)myidx * CD_;
  float acc[8][4] = {};
  for (int kc = 0; kc < CD_; kc += 32) {
    __syncthreads();
    {
      int kk = tid >> 4, rq = tid & 15;
      *(float4*)&At[kk * 64 + rq * 4] =
          *(const float4*)&w_outT[(size_t)(kc + kk) * D_ + d0 + rq * 4];
    }
#pragma unroll
    for (int i = 0; i < 4; ++i) {
      int kg = kq * 4 + i;
      float4 v = *(const float4*)&myrow[kc + kg * 4];
      Bt[(kg * 4 + 0) * 256 + t_l] = v.x;
      Bt[(kg * 4 + 1) * 256 + t_l] = v.y;
      Bt[(kg * 4 + 2) * 256 + t_l] = v.z;
      Bt[(kg * 4 + 3) * 256 + t_l] = v.w;
    }
    __syncthreads();
#pragma unroll 8
    for (int kk = 0; kk < 32; ++kk) {
      float a[8], bv[4];
      *(float4*)&a[0] = *(const float4*)&At[kk * 64 + ty * 8];
      *(float4*)&a[4] = *(const float4*)&At[kk * 64 + ty * 8 + 4];
      *(float4*)&bv[0] = *(const float4*)&Bt[kk * 256 + tx * 4];
#pragma unroll
      for (int j = 0; j < 8; ++j)
#pragma unroll
        for (int m = 0; m < 4; ++m)
          acc[j][m] = fmaf(a[j], bv[m], acc[j][m]);
    }
  }
#pragma unroll
  for (int j = 0; j < 8; ++j) {
    int d = d0 + ty * 8 + j;
    float bias = out_bias[d];
    float4 o;
    o.x = acc[j][0] + bias; o.y = acc[j][1] + bias;
    o.z = acc[j][2] + bias; o.w = acc[j][3] + bias;
    *(float4*)&out[OUT_ZQ + (size_t)(b * D_ + d) * T_ + t0 + tx * 4] = o;
  }
}

extern "C" void kernel_launch(void* const* d_in, const int* in_sizes, int n_in,
                              void* d_out, int out_size, void* d_ws,
                              size_t ws_size, hipStream_t stream) {
  const float* z     = (const float*)d_in[0];
  const float* in_v  = (const float*)d_in[1];
  const float* in_g  = (const float*)d_in[2];
  const float* in_b  = (const float*)d_in[3];
  const float* out_v = (const float*)d_in[4];
  const float* out_g = (const float*)d_in[5];
  const float* out_b = (const float*)d_in[6];
  const float* cb    = (const float*)d_in[7];
  float* out = (float*)d_out;
  float* ws  = (float*)d_ws;

  float* cbT    = ws + WS_CBT;
  float* w_inT  = ws + WS_WINT;
  float* w_outT = ws + WS_WOUTT;
  float* c2     = ws + WS_C2;
  int*   idxw   = (int*)(ws + WS_IDX);

  prep_win<<<CD_, 256, 0, stream>>>(in_v, in_g, w_inT);
  prep_wout<<<D_, 256, 0, stream>>>(out_v, out_g, w_outT);
  prep_cbt<<<dim3(CS_ / 64, CD_ / 64), 256, 0, stream>>>(cb, cbT);
  prep_c2<<<CS_ / 4, 256, 0, stream>>>(cb, c2);

  ze_gemm<<<dim3(T_ / 256, CD_ / 64, B_), 512, 0, stream>>>(z, w_inT, in_b, out);
  vq_argmin<<<(B_ * T_) / 64, 512, 0, stream>>>(out + OUT_ZE, cbT, c2, out, idxw);
  zq_gemm<<<dim3(T_ / 256, D_ / 64, B_), 512, 0, stream>>>(cb, w_outT, out_b, idxw, out);
}

// Round 2
// 1112.363 us; speedup vs baseline: 1.0016x; 1.0016x over previous
//
#include <hip/hip_runtime.h>
#include <math.h>

// Problem constants
#define B_  8
#define D_  1024
#define T_  2048
#define CD_ 256
#define CS_ 8192

// ws layout (in floats). Total ~10.6 MB.
#define WS_CBT   0                       // cbT [CD][CS]
#define WS_WINT  (CD_*CS_)               // w_inT [D][CD]
#define WS_WOUTT (WS_WINT + D_*CD_)      // w_outT [CD][D]
#define WS_C2    (WS_WOUTT + CD_*D_)     // c2 [CS]
#define WS_IDX   (WS_C2 + CS_)           // int idx [B*T]

// d_out layout (floats): z_q, indices(as float), z_e
#define OUT_ZQ  0
#define OUT_IDX (B_*D_*T_)
#define OUT_ZE  (OUT_IDX + B_*T_)

__device__ __forceinline__ float wave_sum64(float v) {
#pragma unroll
  for (int off = 32; off >= 1; off >>= 1) v += __shfl_xor(v, off);
  return v;
}

// ---- prep: w_inT[d][c] = in_g[c] * in_v[c][d] / ||in_v[c,:]|| ----
__global__ void prep_win(const float* __restrict__ in_v,
                         const float* __restrict__ in_g,
                         float* __restrict__ w_inT) {
  int c = blockIdx.x, tid = threadIdx.x;  // 256 threads
  float v[4]; float s = 0.f;
#pragma unroll
  for (int i = 0; i < 4; ++i) {
    v[i] = in_v[c * D_ + tid + 256 * i];
    s = fmaf(v[i], v[i], s);
  }
  s = wave_sum64(s);
  __shared__ float sh[4];
  if ((tid & 63) == 0) sh[tid >> 6] = s;
  __syncthreads();
  float tot = sh[0] + sh[1] + sh[2] + sh[3];
  float scale = in_g[c] / sqrtf(tot);
#pragma unroll
  for (int i = 0; i < 4; ++i)
    w_inT[(tid + 256 * i) * CD_ + c] = v[i] * scale;
}

// ---- prep: w_outT[c][d] = out_g[d] * out_v[d][c] / ||out_v[d,:]|| ----
__global__ void prep_wout(const float* __restrict__ out_v,
                          const float* __restrict__ out_g,
                          float* __restrict__ w_outT) {
  int d = blockIdx.x, tid = threadIdx.x;  // 256 threads, c = tid
  float v = out_v[d * CD_ + tid];
  float s = wave_sum64(v * v);
  __shared__ float sh[4];
  if ((tid & 63) == 0) sh[tid >> 6] = s;
  __syncthreads();
  float tot = sh[0] + sh[1] + sh[2] + sh[3];
  float scale = out_g[d] / sqrtf(tot);
  w_outT[tid * D_ + d] = v * scale;
}

// ---- prep: cbT[c][s] = codebook[s][c] (tiled LDS transpose) ----
__global__ void prep_cbt(const float* __restrict__ cb, float* __restrict__ cbT) {
  __shared__ float tile[64 * 65];
  int s0 = blockIdx.x * 64, c0 = blockIdx.y * 64;
  int tid = threadIdx.x;  // 256
#pragma unroll
  for (int i = 0; i < 4; ++i) {
    int lin = tid + 256 * i;
    int sr = lin >> 4, cq = lin & 15;
    float4 v = *(const float4*)&cb[(size_t)(s0 + sr) * CD_ + c0 + cq * 4];
    float* p = &tile[sr * 65 + cq * 4];
    p[0] = v.x; p[1] = v.y; p[2] = v.z; p[3] = v.w;
  }
  __syncthreads();
#pragma unroll
  for (int i = 0; i < 4; ++i) {
    int lin = tid + 256 * i;
    int c = lin >> 4, sq = lin & 15;
    float4 v;
    v.x = tile[(sq * 4 + 0) * 65 + c];
    v.y = tile[(sq * 4 + 1) * 65 + c];
    v.z = tile[(sq * 4 + 2) * 65 + c];
    v.w = tile[(sq * 4 + 3) * 65 + c];
    *(float4*)&cbT[(size_t)(c0 + c) * CS_ + s0 + sq * 4] = v;
  }
}

// ---- prep: c2[s] = sum_c codebook[s][c]^2 ----
__global__ void prep_c2(const float* __restrict__ cb, float* __restrict__ c2) {
  int tid = threadIdx.x;  // 256 = 4 waves, one row per wave
  int w = tid >> 6, lane = tid & 63;
  int s = blockIdx.x * 4 + w;
  float acc = 0.f;
#pragma unroll
  for (int i = 0; i < 4; ++i) {
    float v = cb[(size_t)s * CD_ + lane + 64 * i];
    acc = fmaf(v, v, acc);
  }
  acc = wave_sum64(acc);
  if (lane == 0) c2[s] = acc;
}

// ---- K1: z_e[b][c][t] = sum_d w_in[c][d]*z[b][d][t] + in_b[c] ----
// tile: 64 c-rows x 256 t-cols, TK=32, 512 threads, microtile 8x4
__global__ __launch_bounds__(512) void ze_gemm(
    const float* __restrict__ z, const float* __restrict__ w_inT,
    const float* __restrict__ in_b, float* __restrict__ out) {
  __shared__ __align__(16) float At[32 * 64];
  __shared__ __align__(16) float Bt[32 * 256];
  int tid = threadIdx.x, tx = tid & 63, ty = tid >> 6;
  int t0 = blockIdx.x * 256, c0 = blockIdx.y * 64, b = blockIdx.z;
  const float* zb = z + (size_t)b * D_ * T_;
  float acc[8][4] = {};
  for (int kc = 0; kc < D_; kc += 32) {
    __syncthreads();
    {
      int kk = tid >> 4, rq = tid & 15;
      *(float4*)&At[kk * 64 + rq * 4] =
          *(const float4*)&w_inT[(size_t)(kc + kk) * CD_ + c0 + rq * 4];
    }
    {
      int kk = tid >> 4, tq = tid & 15;
#pragma unroll
      for (int i = 0; i < 4; ++i) {
        int t = tq * 4 + 64 * i;
        *(float4*)&Bt[kk * 256 + t] =
            *(const float4*)&zb[(size_t)(kc + kk) * T_ + t0 + t];
      }
    }
    __syncthreads();
#pragma unroll 8
    for (int kk = 0; kk < 32; ++kk) {
      float a[8], bv[4];
      *(float4*)&a[0] = *(const float4*)&At[kk * 64 + ty * 8];
      *(float4*)&a[4] = *(const float4*)&At[kk * 64 + ty * 8 + 4];
      *(float4*)&bv[0] = *(const float4*)&Bt[kk * 256 + tx * 4];
#pragma unroll
      for (int j = 0; j < 8; ++j)
#pragma unroll
        for (int m = 0; m < 4; ++m)
          acc[j][m] = fmaf(a[j], bv[m], acc[j][m]);
    }
  }
#pragma unroll
  for (int j = 0; j < 8; ++j) {
    int c = c0 + ty * 8 + j;
    float bias = in_b[c];
    float4 o;
    o.x = acc[j][0] + bias; o.y = acc[j][1] + bias;
    o.z = acc[j][2] + bias; o.w = acc[j][3] + bias;
    *(float4*)&out[OUT_ZE + (size_t)(b * CD_ + c) * T_ + t0 + tx * 4] = o;
  }
}

// ---- K2: fused distance + argmin ----
// block: 64 rows (n), all 8192 codes. 512 threads (tx 0..63 codes, ty 0..7 rows)
// microtile 8 rows x 8 codes; codes per lane are split into two contiguous
// float4 groups {tx*4, 256+tx*4} so each ds_read_b128 is lane-contiguous
// (16 B/lane stride) -> conflict-free, vs the old tx*8 (32 B stride, 16-way).
__global__ __launch_bounds__(512) void vq_argmin(
    const float* __restrict__ ze, const float* __restrict__ cbT,
    const float* __restrict__ c2, float* __restrict__ out,
    int* __restrict__ idx_ws) {
  __shared__ __align__(16) float At[CD_ * 64];   // 64 KB
  __shared__ __align__(16) float Bt[32 * 512];   // 64 KB
  float* e2s = Bt;  // aliased: used before first Bt staging, barrier-protected
  int tid = threadIdx.x, tx = tid & 63, ty = tid >> 6;
  int n0 = blockIdx.x * 64;
  int b = n0 >> 11, t0 = n0 & (T_ - 1);
  const float* zeb = ze + (size_t)b * CD_ * T_ + t0;
  // stage full enc tile: At[k][r] = z_e[b][k][t0+r]
#pragma unroll
  for (int i = 0; i < 8; ++i) {
    int lin = tid + 512 * i;
    int k = lin >> 4, rq = lin & 15;
    *(float4*)&At[k * 64 + rq * 4] =
        *(const float4*)&zeb[(size_t)k * T_ + rq * 4];
  }
  __syncthreads();
  if (tid < 64) {
    float s = 0.f;
    for (int k = 0; k < CD_; ++k) {
      float v = At[k * 64 + tid];
      s = fmaf(v, v, s);
    }
    e2s[tid] = s;
  }
  __syncthreads();
  float e2r[8];
#pragma unroll
  for (int j = 0; j < 8; ++j) e2r[j] = e2s[ty * 8 + j];
  float bestv[8]; int besti[8];
#pragma unroll
  for (int j = 0; j < 8; ++j) { bestv[j] = 3.4e38f; besti[j] = 0; }

  for (int s0 = 0; s0 < CS_; s0 += 512) {
    float acc[8][8] = {};
    float c2v[8];
    *(float4*)&c2v[0] = *(const float4*)&c2[s0 + tx * 4];
    *(float4*)&c2v[4] = *(const float4*)&c2[s0 + 256 + tx * 4];
    for (int kc = 0; kc < CD_; kc += 32) {
      __syncthreads();
#pragma unroll
      for (int i = 0; i < 8; ++i) {
        int lin = tid + 512 * i;
        int kk = lin >> 7, cq = lin & 127;
        *(float4*)&Bt[kk * 512 + cq * 4] =
            *(const float4*)&cbT[(size_t)(kc + kk) * CS_ + s0 + cq * 4];
      }
      __syncthreads();
#pragma unroll 4
      for (int kk = 0; kk < 32; ++kk) {
        float a[8], bb[8];
        *(float4*)&a[0] = *(const float4*)&At[(kc + kk) * 64 + ty * 8];
        *(float4*)&a[4] = *(const float4*)&At[(kc + kk) * 64 + ty * 8 + 4];
        *(float4*)&bb[0] = *(const float4*)&Bt[kk * 512 + tx * 4];
        *(float4*)&bb[4] = *(const float4*)&Bt[kk * 512 + 256 + tx * 4];
#pragma unroll
        for (int j = 0; j < 8; ++j)
#pragma unroll
          for (int m = 0; m < 8; ++m)
            acc[j][m] = fmaf(a[j], bb[m], acc[j][m]);
      }
    }
    // dist = (e2 - 2*dot) + c2, same association as numpy; strict < keeps
    // first (smallest-index) minimum like jnp.argmax(-dist).
    // code index for acc[j][m]: m<4 -> s0+tx*4+m ; m>=4 -> s0+256+tx*4+(m-4)
#pragma unroll
    for (int j = 0; j < 8; ++j) {
#pragma unroll
      for (int m = 0; m < 4; ++m) {
        float dv = fmaf(-2.f, acc[j][m], e2r[j]) + c2v[m];
        int ci = s0 + tx * 4 + m;
        if (dv < bestv[j]) { bestv[j] = dv; besti[j] = ci; }
      }
#pragma unroll
      for (int m = 4; m < 8; ++m) {
        float dv = fmaf(-2.f, acc[j][m], e2r[j]) + c2v[m];
        int ci = s0 + 256 + tx * 4 + (m - 4);
        if (dv < bestv[j]) { bestv[j] = dv; besti[j] = ci; }
      }
    }
  }
  // per-row reduction across the wave (rows of a wave are ty-uniform)
#pragma unroll
  for (int j = 0; j < 8; ++j) {
    float v = bestv[j]; int bi = besti[j];
#pragma unroll
    for (int off = 32; off >= 1; off >>= 1) {
      float ov = __shfl_xor(v, off);
      int oi = __shfl_xor(bi, off);
      if (ov < v || (ov == v && oi < bi)) { v = ov; bi = oi; }
    }
    bestv[j] = v; besti[j] = bi;
  }
  if (tx == 0) {
#pragma unroll
    for (int j = 0; j < 8; ++j) {
      int n = n0 + ty * 8 + j;
      idx_ws[n] = besti[j];
      out[OUT_IDX + n] = (float)besti[j];
    }
  }
}

// ---- K3: z_q[b][d][t] = sum_c w_out[d][c]*codebook[idx[b][t]][c] + out_b[d]
// tile: 64 d-rows x 256 t-cols, TK=32, 512 threads, microtile 8x4
__global__ __launch_bounds__(512) void zq_gemm(
    const float* __restrict__ cb, const float* __restrict__ w_outT,
    const float* __restrict__ out_bias, const int* __restrict__ idx,
    float* __restrict__ out) {
  __shared__ __align__(16) float At[32 * 64];
  __shared__ __align__(16) float Bt[32 * 256];
  __shared__ int idxs[256];
  int tid = threadIdx.x, tx = tid & 63, ty = tid >> 6;
  int t0 = blockIdx.x * 256, d0 = blockIdx.y * 64, b = blockIdx.z;
  if (tid < 256) idxs[tid] = idx[b * T_ + t0 + tid];
  __syncthreads();
  int t_l = tid & 255, kq = tid >> 8;
  int myidx = idxs[t_l];
  const float* myrow = cb + (size_t)myidx * CD_;
  float acc[8][4] = {};
  for (int kc = 0; kc < CD_; kc += 32) {
    __syncthreads();
    {
      int kk = tid >> 4, rq = tid & 15;
      *(float4*)&At[kk * 64 + rq * 4] =
          *(const float4*)&w_outT[(size_t)(kc + kk) * D_ + d0 + rq * 4];
    }
#pragma unroll
    for (int i = 0; i < 4; ++i) {
      int kg = kq * 4 + i;
      float4 v = *(const float4*)&myrow[kc + kg * 4];
      Bt[(kg * 4 + 0) * 256 + t_l] = v.x;
      Bt[(kg * 4 + 1) * 256 + t_l] = v.y;
      Bt[(kg * 4 + 2) * 256 + t_l] = v.z;
      Bt[(kg * 4 + 3) * 256 + t_l] = v.w;
    }
    __syncthreads();
#pragma unroll 8
    for (int kk = 0; kk < 32; ++kk) {
      float a[8], bv[4];
      *(float4*)&a[0] = *(const float4*)&At[kk * 64 + ty * 8];
      *(float4*)&a[4] = *(const float4*)&At[kk * 64 + ty * 8 + 4];
      *(float4*)&bv[0] = *(const float4*)&Bt[kk * 256 + tx * 4];
#pragma unroll
      for (int j = 0; j < 8; ++j)
#pragma unroll
        for (int m = 0; m < 4; ++m)
          acc[j][m] = fmaf(a[j], bv[m], acc[j][m]);
    }
  }
#pragma unroll
  for (int j = 0; j < 8; ++j) {
    int d = d0 + ty * 8 + j;
    float bias = out_bias[d];
    float4 o;
    o.x = acc[j][0] + bias; o.y = acc[j][1] + bias;
    o.z = acc[j][2] + bias; o.w = acc[j][3] + bias;
    *(float4*)&out[OUT_ZQ + (size_t)(b * D_ + d) * T_ + t0 + tx * 4] = o;
  }
}

extern "C" void kernel_launch(void* const* d_in, const int* in_sizes, int n_in,
                              void* d_out, int out_size, void* d_ws,
                              size_t ws_size, hipStream_t stream) {
  const float* z     = (const float*)d_in[0];
  const float* in_v  = (const float*)d_in[1];
  const float* in_g  = (const float*)d_in[2];
  const float* in_b  = (const float*)d_in[3];
  const float* out_v = (const float*)d_in[4];
  const float* out_g = (const float*)d_in[5];
  const float* out_b = (const float*)d_in[6];
  const float* cb    = (const float*)d_in[7];
  float* out = (float*)d_out;
  float* ws  = (float*)d_ws;

  float* cbT    = ws + WS_CBT;
  float* w_inT  = ws + WS_WINT;
  float* w_outT = ws + WS_WOUTT;
  float* c2     = ws + WS_C2;
  int*   idxw   = (int*)(ws + WS_IDX);

  prep_win<<<CD_, 256, 0, stream>>>(in_v, in_g, w_inT);
  prep_wout<<<D_, 256, 0, stream>>>(out_v, out_g, w_outT);
  prep_cbt<<<dim3(CS_ / 64, CD_ / 64), 256, 0, stream>>>(cb, cbT);
  prep_c2<<<CS_ / 4, 256, 0, stream>>>(cb, c2);

  ze_gemm<<<dim3(T_ / 256, CD_ / 64, B_), 512, 0, stream>>>(z, w_inT, in_b, out);
  vq_argmin<<<(B_ * T_) / 64, 512, 0, stream>>>(out + OUT_ZE, cbT, c2, out, idxw);
  zq_gemm<<<dim3(T_ / 256, D_ / 64, B_), 512, 0, stream>>>(cb, w_outT, out_b, idxw, out);
}

// Round 3
// 873.028 us; speedup vs baseline: 1.2762x; 1.2741x over previous
//
#include <hip/hip_runtime.h>
#include <math.h>

// Problem constants
#define B_  8
#define D_  1024
#define T_  2048
#define CD_ 256
#define CS_ 8192
#define N_  (B_*T_)

#define NSPLIT 8
#define CODES_PER_SPLIT (CS_/NSPLIT)   // 1024
#define ROWS_PER_BLOCK 128             // 4 waves * 32 rows
#define DELTA 1.5f                     // score-units; dist window = 2*DELTA

// ws layout (float offsets). Total ~16.4 MB.
#define WS_ZEN   0                        // bf16 [N][256]   (2,097,152 float slots)
#define WS_CBB   2097152                  // bf16 [CS][256]  (1,048,576)
#define WS_WINT  (WS_CBB + 1048576)       // f32 [D][CD]
#define WS_WOUTT (WS_WINT + D_*CD_)       // f32 [CD][D]
#define WS_C2    (WS_WOUTT + CD_*D_)      // f32 [CS]
#define WS_BESTQ (WS_C2 + CS_)            // f32 [NSPLIT][N]
#define WS_CNT   (WS_BESTQ + NSPLIT*N_)   // int [N]
#define WS_CAND  (WS_CNT + N_)            // int [N][16]
#define WS_IDX   (WS_CAND + N_*16)        // int [N]

// d_out layout (floats): z_q, indices(as float), z_e
#define OUT_ZQ  0
#define OUT_IDX (B_*D_*T_)
#define OUT_ZE  (OUT_IDX + B_*T_)

using short8v = __attribute__((ext_vector_type(8))) short;
using float4v = __attribute__((ext_vector_type(4))) float;

__device__ __forceinline__ float wave_sum64(float v) {
#pragma unroll
  for (int off = 32; off >= 1; off >>= 1) v += __shfl_xor(v, off);
  return v;
}

__device__ __forceinline__ unsigned short f2bf_rne(float f) {
  unsigned int u = __float_as_uint(f);
  u += 0x7fffu + ((u >> 16) & 1u);
  return (unsigned short)(u >> 16);
}

// ---- prep: w_inT[d][c] = in_g[c] * in_v[c][d] / ||in_v[c,:]|| ----
__global__ void prep_win(const float* __restrict__ in_v,
                         const float* __restrict__ in_g,
                         float* __restrict__ w_inT) {
  int c = blockIdx.x, tid = threadIdx.x;  // 256 threads
  float v[4]; float s = 0.f;
#pragma unroll
  for (int i = 0; i < 4; ++i) {
    v[i] = in_v[c * D_ + tid + 256 * i];
    s = fmaf(v[i], v[i], s);
  }
  s = wave_sum64(s);
  __shared__ float sh[4];
  if ((tid & 63) == 0) sh[tid >> 6] = s;
  __syncthreads();
  float tot = sh[0] + sh[1] + sh[2] + sh[3];
  float scale = in_g[c] / sqrtf(tot);
#pragma unroll
  for (int i = 0; i < 4; ++i)
    w_inT[(tid + 256 * i) * CD_ + c] = v[i] * scale;
}

// ---- prep: w_outT[c][d] = out_g[d] * out_v[d][c] / ||out_v[d,:]|| ----
__global__ void prep_wout(const float* __restrict__ out_v,
                          const float* __restrict__ out_g,
                          float* __restrict__ w_outT) {
  int d = blockIdx.x, tid = threadIdx.x;  // 256 threads, c = tid
  float v = out_v[d * CD_ + tid];
  float s = wave_sum64(v * v);
  __shared__ float sh[4];
  if ((tid & 63) == 0) sh[tid >> 6] = s;
  __syncthreads();
  float tot = sh[0] + sh[1] + sh[2] + sh[3];
  float scale = out_g[d] / sqrtf(tot);
  w_outT[tid * D_ + d] = v * scale;
}

// ---- prep: c2[s] = sum_c codebook[s][c]^2 ----
__global__ void prep_c2(const float* __restrict__ cb, float* __restrict__ c2) {
  int tid = threadIdx.x;  // 256 = 4 waves, one row per wave
  int w = tid >> 6, lane = tid & 63;
  int s = blockIdx.x * 4 + w;
  float acc = 0.f;
#pragma unroll
  for (int i = 0; i < 4; ++i) {
    float v = cb[(size_t)s * CD_ + lane + 64 * i];
    acc = fmaf(v, v, acc);
  }
  acc = wave_sum64(acc);
  if (lane == 0) c2[s] = acc;
}

// ---- prep: codebook fp32 -> bf16 row-major copy ----
__global__ void cvt_cb(const float* __restrict__ cb, unsigned short* __restrict__ cbb) {
  size_t i = (size_t)blockIdx.x * 256 + threadIdx.x;  // octet index
  float4 v0 = *(const float4*)&cb[i * 8];
  float4 v1 = *(const float4*)&cb[i * 8 + 4];
  float f[8] = {v0.x, v0.y, v0.z, v0.w, v1.x, v1.y, v1.z, v1.w};
  unsigned short us[8];
#pragma unroll
  for (int m = 0; m < 8; ++m) us[m] = f2bf_rne(f[m]);
  *(uint4*)&cbb[i * 8] = *(uint4*)&us[0];
}

// ---- K1: z_e[b][c][t] = sum_d w_in[c][d]*z[b][d][t] + in_b[c] ----
__global__ __launch_bounds__(512) void ze_gemm(
    const float* __restrict__ z, const float* __restrict__ w_inT,
    const float* __restrict__ in_b, float* __restrict__ out) {
  __shared__ __align__(16) float At[32 * 64];
  __shared__ __align__(16) float Bt[32 * 256];
  int tid = threadIdx.x, tx = tid & 63, ty = tid >> 6;
  int t0 = blockIdx.x * 256, c0 = blockIdx.y * 64, b = blockIdx.z;
  const float* zb = z + (size_t)b * D_ * T_;
  float acc[8][4] = {};
  for (int kc = 0; kc < D_; kc += 32) {
    __syncthreads();
    {
      int kk = tid >> 4, rq = tid & 15;
      *(float4*)&At[kk * 64 + rq * 4] =
          *(const float4*)&w_inT[(size_t)(kc + kk) * CD_ + c0 + rq * 4];
    }
    {
      int kk = tid >> 4, tq = tid & 15;
#pragma unroll
      for (int i = 0; i < 4; ++i) {
        int t = tq * 4 + 64 * i;
        *(float4*)&Bt[kk * 256 + t] =
            *(const float4*)&zb[(size_t)(kc + kk) * T_ + t0 + t];
      }
    }
    __syncthreads();
#pragma unroll 8
    for (int kk = 0; kk < 32; ++kk) {
      float a[8], bv[4];
      *(float4*)&a[0] = *(const float4*)&At[kk * 64 + ty * 8];
      *(float4*)&a[4] = *(const float4*)&At[kk * 64 + ty * 8 + 4];
      *(float4*)&bv[0] = *(const float4*)&Bt[kk * 256 + tx * 4];
#pragma unroll
      for (int j = 0; j < 8; ++j)
#pragma unroll
        for (int m = 0; m < 4; ++m)
          acc[j][m] = fmaf(a[j], bv[m], acc[j][m]);
    }
  }
#pragma unroll
  for (int j = 0; j < 8; ++j) {
    int c = c0 + ty * 8 + j;
    float bias = in_b[c];
    float4 o;
    o.x = acc[j][0] + bias; o.y = acc[j][1] + bias;
    o.z = acc[j][2] + bias; o.w = acc[j][3] + bias;
    *(float4*)&out[OUT_ZE + (size_t)(b * CD_ + c) * T_ + t0 + tx * 4] = o;
  }
}

// ---- transpose+convert: z_e [b][c][t] f32 -> zeN [b*T+t][c] bf16 ----
__global__ __launch_bounds__(256) void ze_t(const float* __restrict__ ze,
                                            unsigned short* __restrict__ zeN) {
  __shared__ float tile[64][65];
  int t0 = blockIdx.x * 64, c0 = blockIdx.y * 64, b = blockIdx.z;
  int tid = threadIdx.x;
  int cr = tid >> 4, tq = tid & 15;
#pragma unroll
  for (int i = 0; i < 4; ++i) {
    int c = cr + 16 * i;
    float4 v = *(const float4*)&ze[((size_t)(b * CD_ + c0 + c)) * T_ + t0 + tq * 4];
    tile[c][tq * 4 + 0] = v.x; tile[c][tq * 4 + 1] = v.y;
    tile[c][tq * 4 + 2] = v.z; tile[c][tq * 4 + 3] = v.w;
  }
  __syncthreads();
  int tr = tid >> 2, qc = tid & 3;
  unsigned short us[16];
#pragma unroll
  for (int m = 0; m < 16; ++m) us[m] = f2bf_rne(tile[qc * 16 + m][tr]);
  size_t base = ((size_t)(b * T_ + t0 + tr)) * CD_ + c0 + qc * 16;
  *(uint4*)&zeN[base] = *(uint4*)&us[0];
  *(uint4*)&zeN[base + 8] = *(uint4*)&us[8];
}

// ---- K2: MFMA coarse scan. COLLECT=0: per-row best bf16 score per split.
//      COLLECT=1: append codes with score >= rowbest - DELTA as candidates.
// block: 256 thr = 4 waves; wave owns 32 rows (A-frags register-resident),
// scans its code split in 64-code tiles. score = dot(ze,c) - 0.5*||c||^2.
// MFMA 16x16x32_bf16: C/D col=lane&15 (code), row=(lane>>4)*4+reg.
template <int COLLECT>
__global__ __launch_bounds__(256) void vq_scan(
    const unsigned short* __restrict__ zeN, const unsigned short* __restrict__ cbb,
    const float* __restrict__ c2, float* __restrict__ bestq,
    int* __restrict__ cnt, int* __restrict__ cand) {
  int tid = threadIdx.x;
  int w = tid >> 6, l = tid & 63;
  int rowbase = blockIdx.x * ROWS_PER_BLOCK + w * 32;
  int cq = blockIdx.y;
  int cbase0 = cq * CODES_PER_SPLIT;
  int lrow = l & 15, lg = l >> 4;

  if (COLLECT == 0 && cq == 0 && tid < ROWS_PER_BLOCK)
    cnt[blockIdx.x * ROWS_PER_BLOCK + tid] = 0;

  // A fragments: 2 row-frags x 8 k-steps, 16B contiguous k-slices
  short8v a[2][8];
#pragma unroll
  for (int rf = 0; rf < 2; ++rf)
#pragma unroll
    for (int ks = 0; ks < 8; ++ks)
      a[rf][ks] = *(const short8v*)&zeN[((size_t)(rowbase + rf * 16 + lrow)) * CD_ + ks * 32 + lg * 8];

  float best[8]; int bidx[8]; float thr[8];
#pragma unroll
  for (int s = 0; s < 8; ++s) { best[s] = -3.4e38f; bidx[s] = 0; thr[s] = 0.f; }

  if (COLLECT) {
#pragma unroll
    for (int s = 0; s < 8; ++s) {
      int rf = s >> 2, rg = s & 3;
      int row = rowbase + rf * 16 + lg * 4 + rg;
      float m = -3.4e38f;
#pragma unroll
      for (int q = 0; q < NSPLIT; ++q) m = fmaxf(m, bestq[q * N_ + row]);
      thr[s] = m - DELTA;
    }
  }

  float4v zero4 = {0.f, 0.f, 0.f, 0.f};
  for (int ct = 0; ct < CODES_PER_SPLIT; ct += 64) {
    int cbase = cbase0 + ct;
    float4v acc[2][4];
#pragma unroll
    for (int rf = 0; rf < 2; ++rf)
#pragma unroll
      for (int cf = 0; cf < 4; ++cf) acc[rf][cf] = zero4;
    float c2v[4];
#pragma unroll
    for (int cf = 0; cf < 4; ++cf) c2v[cf] = c2[cbase + cf * 16 + lrow];
#pragma unroll
    for (int cf = 0; cf < 4; ++cf) {
#pragma unroll
      for (int ks = 0; ks < 8; ++ks) {
        short8v bfrag = *(const short8v*)&cbb[((size_t)(cbase + cf * 16 + lrow)) * CD_ + ks * 32 + lg * 8];
        acc[0][cf] = __builtin_amdgcn_mfma_f32_16x16x32_bf16(a[0][ks], bfrag, acc[0][cf], 0, 0, 0);
        acc[1][cf] = __builtin_amdgcn_mfma_f32_16x16x32_bf16(a[1][ks], bfrag, acc[1][cf], 0, 0, 0);
      }
    }
#pragma unroll
    for (int rf = 0; rf < 2; ++rf)
#pragma unroll
      for (int cf = 0; cf < 4; ++cf)
#pragma unroll
        for (int rg = 0; rg < 4; ++rg) {
          float s = acc[rf][cf][rg] - 0.5f * c2v[cf];
          int slot = rf * 4 + rg;
          if (COLLECT) {
            if (s >= thr[slot]) {
              int row = rowbase + rf * 16 + lg * 4 + rg;
              int pos = atomicAdd(&cnt[row], 1);
              if (pos < 16) cand[row * 16 + pos] = cbase + cf * 16 + lrow;
            }
          } else {
            if (s > best[slot]) { best[slot] = s; bidx[slot] = cbase + cf * 16 + lrow; }
          }
        }
  }

  if (!COLLECT) {
#pragma unroll
    for (int s = 0; s < 8; ++s) {
      float v = best[s];
#pragma unroll
      for (int off = 1; off < 16; off <<= 1) v = fmaxf(v, __shfl_xor(v, off));
      best[s] = v;
    }
    if (lrow == 0) {
#pragma unroll
      for (int s = 0; s < 8; ++s) {
        int rf = s >> 2, rg = s & 3;
        int row = rowbase + rf * 16 + lg * 4 + rg;
        bestq[cq * N_ + row] = best[s];
      }
    }
  }
}

// ---- exact fp32 rescore of candidates; lexicographic (dist, idx) min ----
__global__ __launch_bounds__(256) void vq_rescore(
    const float* __restrict__ ze, const float* __restrict__ cb,
    const int* __restrict__ cnt, const int* __restrict__ cand,
    float* __restrict__ out, int* __restrict__ idx_ws) {
  int tid = threadIdx.x;
  int n = blockIdx.x * 64 + (tid >> 2);
  int j = tid & 3;
  int b = n >> 11, t = n & (T_ - 1);
  const float* zr = ze + ((size_t)b * CD_) * T_ + t;  // element k at zr[k*T_]
  int m = cnt[n]; if (m > 16) m = 16;
  float bd = 3.4e38f; int bi = 0x7fffffff;
  for (int i = 0; i < m; ++i) {
    int c = cand[n * 16 + i];
    const float* cr = cb + (size_t)c * CD_;
    float d = 0.f;
    for (int k = j; k < CD_; k += 4) {
      float diff = zr[(size_t)k * T_] - cr[k];
      d = fmaf(diff, diff, d);
    }
    d += __shfl_xor(d, 1);
    d += __shfl_xor(d, 2);
    if (d < bd || (d == bd && c < bi)) { bd = d; bi = c; }
  }
  if (j == 0) {
    idx_ws[n] = bi;
    out[OUT_IDX + n] = (float)bi;
  }
}

// ---- K3: z_q[b][d][t] = sum_c w_out[d][c]*codebook[idx[b][t]][c] + out_b[d]
__global__ __launch_bounds__(512) void zq_gemm(
    const float* __restrict__ cb, const float* __restrict__ w_outT,
    const float* __restrict__ out_bias, const int* __restrict__ idx,
    float* __restrict__ out) {
  __shared__ __align__(16) float At[32 * 64];
  __shared__ __align__(16) float Bt[32 * 256];
  __shared__ int idxs[256];
  int tid = threadIdx.x, tx = tid & 63, ty = tid >> 6;
  int t0 = blockIdx.x * 256, d0 = blockIdx.y * 64, b = blockIdx.z;
  if (tid < 256) idxs[tid] = idx[b * T_ + t0 + tid];
  __syncthreads();
  int t_l = tid & 255, kq = tid >> 8;
  int myidx = idxs[t_l];
  const float* myrow = cb + (size_t)myidx * CD_;
  float acc[8][4] = {};
  for (int kc = 0; kc < CD_; kc += 32) {
    __syncthreads();
    {
      int kk = tid >> 4, rq = tid & 15;
      *(float4*)&At[kk * 64 + rq * 4] =
          *(const float4*)&w_outT[(size_t)(kc + kk) * D_ + d0 + rq * 4];
    }
#pragma unroll
    for (int i = 0; i < 4; ++i) {
      int kg = kq * 4 + i;
      float4 v = *(const float4*)&myrow[kc + kg * 4];
      Bt[(kg * 4 + 0) * 256 + t_l] = v.x;
      Bt[(kg * 4 + 1) * 256 + t_l] = v.y;
      Bt[(kg * 4 + 2) * 256 + t_l] = v.z;
      Bt[(kg * 4 + 3) * 256 + t_l] = v.w;
    }
    __syncthreads();
#pragma unroll 8
    for (int kk = 0; kk < 32; ++kk) {
      float a[8], bv[4];
      *(float4*)&a[0] = *(const float4*)&At[kk * 64 + ty * 8];
      *(float4*)&a[4] = *(const float4*)&At[kk * 64 + ty * 8 + 4];
      *(float4*)&bv[0] = *(const float4*)&Bt[kk * 256 + tx * 4];
#pragma unroll
      for (int j = 0; j < 8; ++j)
#pragma unroll
        for (int m = 0; m < 4; ++m)
          acc[j][m] = fmaf(a[j], bv[m], acc[j][m]);
    }
  }
#pragma unroll
  for (int j = 0; j < 8; ++j) {
    int d = d0 + ty * 8 + j;
    float bias = out_bias[d];
    float4 o;
    o.x = acc[j][0] + bias; o.y = acc[j][1] + bias;
    o.z = acc[j][2] + bias; o.w = acc[j][3] + bias;
    *(float4*)&out[OUT_ZQ + (size_t)(b * D_ + d) * T_ + t0 + tx * 4] = o;
  }
}

extern "C" void kernel_launch(void* const* d_in, const int* in_sizes, int n_in,
                              void* d_out, int out_size, void* d_ws,
                              size_t ws_size, hipStream_t stream) {
  const float* z     = (const float*)d_in[0];
  const float* in_v  = (const float*)d_in[1];
  const float* in_g  = (const float*)d_in[2];
  const float* in_b  = (const float*)d_in[3];
  const float* out_v = (const float*)d_in[4];
  const float* out_g = (const float*)d_in[5];
  const float* out_b = (const float*)d_in[6];
  const float* cb    = (const float*)d_in[7];
  float* out = (float*)d_out;
  float* ws  = (float*)d_ws;

  unsigned short* zeN = (unsigned short*)(ws + WS_ZEN);
  unsigned short* cbb = (unsigned short*)(ws + WS_CBB);
  float* w_inT  = ws + WS_WINT;
  float* w_outT = ws + WS_WOUTT;
  float* c2     = ws + WS_C2;
  float* bestq  = ws + WS_BESTQ;
  int*   cnt    = (int*)(ws + WS_CNT);
  int*   cand   = (int*)(ws + WS_CAND);
  int*   idxw   = (int*)(ws + WS_IDX);

  prep_win<<<CD_, 256, 0, stream>>>(in_v, in_g, w_inT);
  prep_wout<<<D_, 256, 0, stream>>>(out_v, out_g, w_outT);
  prep_c2<<<CS_ / 4, 256, 0, stream>>>(cb, c2);
  cvt_cb<<<(CS_ * CD_ / 8) / 256, 256, 0, stream>>>(cb, cbb);

  ze_gemm<<<dim3(T_ / 256, CD_ / 64, B_), 512, 0, stream>>>(z, w_inT, in_b, out);
  ze_t<<<dim3(T_ / 64, CD_ / 64, B_), 256, 0, stream>>>(out + OUT_ZE, zeN);

  vq_scan<0><<<dim3(N_ / ROWS_PER_BLOCK, NSPLIT), 256, 0, stream>>>(
      zeN, cbb, c2, bestq, cnt, cand);
  vq_scan<1><<<dim3(N_ / ROWS_PER_BLOCK, NSPLIT), 256, 0, stream>>>(
      zeN, cbb, c2, bestq, cnt, cand);
  vq_rescore<<<N_ / 64, 256, 0, stream>>>(out + OUT_ZE, cb, cnt, cand, out, idxw);

  zq_gemm<<<dim3(T_ / 256, D_ / 64, B_), 512, 0, stream>>>(cb, w_outT, out_b, idxw, out);
}

// Round 4
// 502.174 us; speedup vs baseline: 2.2186x; 1.7385x over previous
//
#include <hip/hip_runtime.h>
#include <math.h>

// Problem constants
#define B_  8
#define D_  1024
#define T_  2048
#define CD_ 256
#define CS_ 8192
#define N_  (B_*T_)

#define NSPLIT 8
#define CODES_PER_SPLIT (CS_/NSPLIT)   // 1024
#define DELTA 1.5f                     // score-units; >> 2*bf16 dot error

// scan geometry: 4 waves * 64 rows = 256 rows/block; 64-code LDS tiles
#define SCAN_WAVES 4
#define ROWS_PER_WAVE 64
#define SCAN_ROWS 256
#define TILE_CODES 64

// ws layout (float offsets). Total ~16.4 MB.
#define WS_ZEN   0                        // bf16 [N][256]   (2,097,152 float slots)
#define WS_CBB   2097152                  // bf16 [CS][256]  (1,048,576)
#define WS_WINT  (WS_CBB + 1048576)       // f32 [D][CD]
#define WS_WOUTT (WS_WINT + D_*CD_)       // f32 [CD][D]
#define WS_C2    (WS_WOUTT + CD_*D_)      // f32 [CS]
#define WS_BESTQ (WS_C2 + CS_)            // f32 [NSPLIT][N]; row 0 becomes thr
#define WS_CNT   (WS_BESTQ + NSPLIT*N_)   // int [N]
#define WS_CAND  (WS_CNT + N_)            // int [N][16]
#define WS_IDX   (WS_CAND + N_*16)        // int [N]

// d_out layout (floats): z_q, indices(as float), z_e
#define OUT_ZQ  0
#define OUT_IDX (B_*D_*T_)
#define OUT_ZE  (OUT_IDX + B_*T_)

using short8v = __attribute__((ext_vector_type(8))) short;
using float4v = __attribute__((ext_vector_type(4))) float;

__device__ __forceinline__ float wave_sum64(float v) {
#pragma unroll
  for (int off = 32; off >= 1; off >>= 1) v += __shfl_xor(v, off);
  return v;
}

__device__ __forceinline__ unsigned short f2bf_rne(float f) {
  unsigned int u = __float_as_uint(f);
  u += 0x7fffu + ((u >> 16) & 1u);
  return (unsigned short)(u >> 16);
}

__device__ __forceinline__ void gload_lds16(const void* g, void* l) {
  __builtin_amdgcn_global_load_lds(
      (const __attribute__((address_space(1))) void*)g,
      (__attribute__((address_space(3))) void*)l, 16, 0, 0);
}

// ---- prep: w_inT[d][c] = in_g[c] * in_v[c][d] / ||in_v[c,:]|| ----
__global__ void prep_win(const float* __restrict__ in_v,
                         const float* __restrict__ in_g,
                         float* __restrict__ w_inT) {
  int c = blockIdx.x, tid = threadIdx.x;  // 256 threads
  float v[4]; float s = 0.f;
#pragma unroll
  for (int i = 0; i < 4; ++i) {
    v[i] = in_v[c * D_ + tid + 256 * i];
    s = fmaf(v[i], v[i], s);
  }
  s = wave_sum64(s);
  __shared__ float sh[4];
  if ((tid & 63) == 0) sh[tid >> 6] = s;
  __syncthreads();
  float tot = sh[0] + sh[1] + sh[2] + sh[3];
  float scale = in_g[c] / sqrtf(tot);
#pragma unroll
  for (int i = 0; i < 4; ++i)
    w_inT[(tid + 256 * i) * CD_ + c] = v[i] * scale;
}

// ---- prep: w_outT[c][d] = out_g[d] * out_v[d][c] / ||out_v[d,:]|| ----
__global__ void prep_wout(const float* __restrict__ out_v,
                          const float* __restrict__ out_g,
                          float* __restrict__ w_outT) {
  int d = blockIdx.x, tid = threadIdx.x;  // 256 threads, c = tid
  float v = out_v[d * CD_ + tid];
  float s = wave_sum64(v * v);
  __shared__ float sh[4];
  if ((tid & 63) == 0) sh[tid >> 6] = s;
  __syncthreads();
  float tot = sh[0] + sh[1] + sh[2] + sh[3];
  float scale = out_g[d] / sqrtf(tot);
  w_outT[tid * D_ + d] = v * scale;
}

// ---- prep: c2[s] = sum_c codebook[s][c]^2 ----
__global__ void prep_c2(const float* __restrict__ cb, float* __restrict__ c2) {
  int tid = threadIdx.x;  // 256 = 4 waves, one row per wave
  int w = tid >> 6, lane = tid & 63;
  int s = blockIdx.x * 4 + w;
  float acc = 0.f;
#pragma unroll
  for (int i = 0; i < 4; ++i) {
    float v = cb[(size_t)s * CD_ + lane + 64 * i];
    acc = fmaf(v, v, acc);
  }
  acc = wave_sum64(acc);
  if (lane == 0) c2[s] = acc;
}

// ---- prep: codebook fp32 -> bf16 row-major copy ----
__global__ void cvt_cb(const float* __restrict__ cb, unsigned short* __restrict__ cbb) {
  size_t i = (size_t)blockIdx.x * 256 + threadIdx.x;  // octet index
  float4 v0 = *(const float4*)&cb[i * 8];
  float4 v1 = *(const float4*)&cb[i * 8 + 4];
  float f[8] = {v0.x, v0.y, v0.z, v0.w, v1.x, v1.y, v1.z, v1.w};
  unsigned short us[8];
#pragma unroll
  for (int m = 0; m < 8; ++m) us[m] = f2bf_rne(f[m]);
  *(uint4*)&cbb[i * 8] = *(uint4*)&us[0];
}

// ---- K1: z_e[b][c][t] = sum_d w_in[c][d]*z[b][d][t] + in_b[c] ----
__global__ __launch_bounds__(512) void ze_gemm(
    const float* __restrict__ z, const float* __restrict__ w_inT,
    const float* __restrict__ in_b, float* __restrict__ out) {
  __shared__ __align__(16) float At[32 * 64];
  __shared__ __align__(16) float Bt[32 * 256];
  int tid = threadIdx.x, tx = tid & 63, ty = tid >> 6;
  int t0 = blockIdx.x * 256, c0 = blockIdx.y * 64, b = blockIdx.z;
  const float* zb = z + (size_t)b * D_ * T_;
  float acc[8][4] = {};
  for (int kc = 0; kc < D_; kc += 32) {
    __syncthreads();
    {
      int kk = tid >> 4, rq = tid & 15;
      *(float4*)&At[kk * 64 + rq * 4] =
          *(const float4*)&w_inT[(size_t)(kc + kk) * CD_ + c0 + rq * 4];
    }
    {
      int kk = tid >> 4, tq = tid & 15;
#pragma unroll
      for (int i = 0; i < 4; ++i) {
        int t = tq * 4 + 64 * i;
        *(float4*)&Bt[kk * 256 + t] =
            *(const float4*)&zb[(size_t)(kc + kk) * T_ + t0 + t];
      }
    }
    __syncthreads();
#pragma unroll 8
    for (int kk = 0; kk < 32; ++kk) {
      float a[8], bv[4];
      *(float4*)&a[0] = *(const float4*)&At[kk * 64 + ty * 8];
      *(float4*)&a[4] = *(const float4*)&At[kk * 64 + ty * 8 + 4];
      *(float4*)&bv[0] = *(const float4*)&Bt[kk * 256 + tx * 4];
#pragma unroll
      for (int j = 0; j < 8; ++j)
#pragma unroll
        for (int m = 0; m < 4; ++m)
          acc[j][m] = fmaf(a[j], bv[m], acc[j][m]);
    }
  }
#pragma unroll
  for (int j = 0; j < 8; ++j) {
    int c = c0 + ty * 8 + j;
    float bias = in_b[c];
    float4 o;
    o.x = acc[j][0] + bias; o.y = acc[j][1] + bias;
    o.z = acc[j][2] + bias; o.w = acc[j][3] + bias;
    *(float4*)&out[OUT_ZE + (size_t)(b * CD_ + c) * T_ + t0 + tx * 4] = o;
  }
}

// ---- transpose+convert: z_e [b][c][t] f32 -> zeN [b*T+t][c] bf16 ----
__global__ __launch_bounds__(256) void ze_t(const float* __restrict__ ze,
                                            unsigned short* __restrict__ zeN) {
  __shared__ float tile[64][65];
  int t0 = blockIdx.x * 64, c0 = blockIdx.y * 64, b = blockIdx.z;
  int tid = threadIdx.x;
  int cr = tid >> 4, tq = tid & 15;
#pragma unroll
  for (int i = 0; i < 4; ++i) {
    int c = cr + 16 * i;
    float4 v = *(const float4*)&ze[((size_t)(b * CD_ + c0 + c)) * T_ + t0 + tq * 4];
    tile[c][tq * 4 + 0] = v.x; tile[c][tq * 4 + 1] = v.y;
    tile[c][tq * 4 + 2] = v.z; tile[c][tq * 4 + 3] = v.w;
  }
  __syncthreads();
  int tr = tid >> 2, qc = tid & 3;
  unsigned short us[16];
#pragma unroll
  for (int m = 0; m < 16; ++m) us[m] = f2bf_rne(tile[qc * 16 + m][tr]);
  size_t base = ((size_t)(b * T_ + t0 + tr)) * CD_ + c0 + qc * 16;
  *(uint4*)&zeN[base] = *(uint4*)&us[0];
  *(uint4*)&zeN[base + 8] = *(uint4*)&us[8];
}

// ---- K2: MFMA coarse scan, LDS-staged double-buffered.
// 4 waves x 64 rows; A register-resident (4 rf x 8 ks short8v).
// 64-code tiles in LDS via global_load_lds(16B), XOR-swizzle
// byte ^= ((code&7)<<4) applied on the pre-swizzled GLOBAL source and on the
// ds_read address (rule: both-sides-or-neither). score = dot - 0.5*||c||^2.
// COLLECT=0: per-row best score per split -> bestq[cq][row].
// COLLECT=1: append codes with score >= thr[row] (thr = rowmax - DELTA).
template <int COLLECT>
__global__ __launch_bounds__(256, 2) void vq_scan(
    const unsigned short* __restrict__ zeN, const unsigned short* __restrict__ cbb,
    const float* __restrict__ c2, float* __restrict__ bestq,
    int* __restrict__ cnt, int* __restrict__ cand) {
  __shared__ __align__(16) unsigned short smem[2][TILE_CODES * CD_];  // 2 x 32 KB
  int tid = threadIdx.x;
  int w = tid >> 6, l = tid & 63;
  int lrow = l & 15, lg = l >> 4;
  int rowbase = blockIdx.x * SCAN_ROWS + w * ROWS_PER_WAVE;
  int cq = blockIdx.y;
  int cbase0 = cq * CODES_PER_SPLIT;

  if (COLLECT == 0 && cq == 0)
    cnt[blockIdx.x * SCAN_ROWS + tid] = 0;

  // A fragments: 4 row-frags x 8 k-steps (16B contiguous k-slices)
  short8v a[4][8];
#pragma unroll
  for (int rf = 0; rf < 4; ++rf)
#pragma unroll
    for (int ks = 0; ks < 8; ++ks)
      a[rf][ks] = *(const short8v*)&zeN[((size_t)(rowbase + rf * 16 + lrow)) * CD_ + ks * 32 + lg * 8];

  float best[16];
  float thr[16];
#pragma unroll
  for (int s = 0; s < 16; ++s) best[s] = -3.4e38f;
  if (COLLECT) {
#pragma unroll
    for (int s = 0; s < 16; ++s) {
      int rf = s >> 2, rg = s & 3;
      thr[s] = bestq[rowbase + rf * 16 + lg * 4 + rg];  // rowmax - DELTA
    }
  }

  // staging lane constants: lane l writes linear LDS bytes [s*1024 + l*16)
  // for segment s = w*8 + r; covers code = w*16 + r*2 + (l>>5).
  int lhalf = l >> 5;
  int lcol = (l & 31) * 16;
  char* smem_b = (char*)&smem[0][0];
  const char* cbb_b = (const char*)cbb;
  int xsw = (lrow & 7) << 4;

  auto stage = [&](int buf, int cbase) {
#pragma unroll
    for (int r = 0; r < 8; ++r) {
      int code = w * 16 + r * 2 + lhalf;
      size_t goff = (size_t)(cbase + code) * 512 + (size_t)(lcol ^ ((code & 7) << 4));
      gload_lds16(cbb_b + goff, smem_b + buf * 32768 + (w * 8 + r) * 1024);
    }
  };

  stage(0, cbase0);
  __syncthreads();

  for (int t = 0; t < CODES_PER_SPLIT / TILE_CODES; ++t) {
    int buf = t & 1;
    int cbase = cbase0 + t * TILE_CODES;
    if (t + 1 < CODES_PER_SPLIT / TILE_CODES)
      stage(buf ^ 1, cbase + TILE_CODES);

    const char* bufb = smem_b + buf * 32768;
#pragma unroll
    for (int cf = 0; cf < 4; ++cf) {
      const char* bbase = bufb + (cf * 16 + lrow) * 512;
      float c2v = c2[cbase + cf * 16 + lrow];
      float4v acc[4];
#pragma unroll
      for (int rf = 0; rf < 4; ++rf) acc[rf] = (float4v){0.f, 0.f, 0.f, 0.f};
#pragma unroll
      for (int ks = 0; ks < 8; ++ks) {
        short8v bfrag = *(const short8v*)(bbase + ((ks * 64 + lg * 16) ^ xsw));
        acc[0] = __builtin_amdgcn_mfma_f32_16x16x32_bf16(a[0][ks], bfrag, acc[0], 0, 0, 0);
        acc[1] = __builtin_amdgcn_mfma_f32_16x16x32_bf16(a[1][ks], bfrag, acc[1], 0, 0, 0);
        acc[2] = __builtin_amdgcn_mfma_f32_16x16x32_bf16(a[2][ks], bfrag, acc[2], 0, 0, 0);
        acc[3] = __builtin_amdgcn_mfma_f32_16x16x32_bf16(a[3][ks], bfrag, acc[3], 0, 0, 0);
      }
      int ci = cbase + cf * 16 + lrow;
      float half_c2 = 0.5f * c2v;
#pragma unroll
      for (int rf = 0; rf < 4; ++rf)
#pragma unroll
        for (int rg = 0; rg < 4; ++rg) {
          float sc = acc[rf][rg] - half_c2;
          int slot = rf * 4 + rg;
          if (COLLECT) {
            if (sc >= thr[slot]) {
              int row = rowbase + rf * 16 + lg * 4 + rg;
              int pos = atomicAdd(&cnt[row], 1);
              if (pos < 16) cand[row * 16 + pos] = ci;
            }
          } else {
            best[slot] = fmaxf(best[slot], sc);
          }
        }
    }
    __syncthreads();
  }

  if (!COLLECT) {
#pragma unroll
    for (int s = 0; s < 16; ++s) {
      float v = best[s];
#pragma unroll
      for (int off = 1; off < 16; off <<= 1) v = fmaxf(v, __shfl_xor(v, off));
      best[s] = v;
    }
    if (lrow == 0) {
#pragma unroll
      for (int s = 0; s < 16; ++s) {
        int rf = s >> 2, rg = s & 3;
        bestq[cq * N_ + rowbase + rf * 16 + lg * 4 + rg] = best[s];
      }
    }
  }
}

// ---- fold split maxima into per-row threshold, in place (row 0 of bestq) ----
__global__ __launch_bounds__(256) void vq_rowthr(float* __restrict__ bestq) {
  int n = blockIdx.x * 256 + threadIdx.x;
  float m = bestq[n];
#pragma unroll
  for (int q = 1; q < NSPLIT; ++q) m = fmaxf(m, bestq[q * N_ + n]);
  bestq[n] = m - DELTA;
}

// ---- exact fp32 rescore of candidates; lexicographic (dist, idx) min ----
__global__ __launch_bounds__(256) void vq_rescore(
    const float* __restrict__ ze, const float* __restrict__ cb,
    const int* __restrict__ cnt, const int* __restrict__ cand,
    float* __restrict__ out, int* __restrict__ idx_ws) {
  int tid = threadIdx.x;
  int n = blockIdx.x * 64 + (tid >> 2);
  int j = tid & 3;
  int b = n >> 11, t = n & (T_ - 1);
  const float* zr = ze + ((size_t)b * CD_) * T_ + t;  // element k at zr[k*T_]
  int m = cnt[n]; if (m > 16) m = 16;
  float bd = 3.4e38f; int bi = 0x7fffffff;
  for (int i = 0; i < m; ++i) {
    int c = cand[n * 16 + i];
    const float* cr = cb + (size_t)c * CD_;
    float d = 0.f;
    for (int k = j; k < CD_; k += 4) {
      float diff = zr[(size_t)k * T_] - cr[k];
      d = fmaf(diff, diff, d);
    }
    d += __shfl_xor(d, 1);
    d += __shfl_xor(d, 2);
    if (d < bd || (d == bd && c < bi)) { bd = d; bi = c; }
  }
  if (j == 0) {
    idx_ws[n] = bi;
    out[OUT_IDX + n] = (float)bi;
  }
}

// ---- K3: z_q[b][d][t] = sum_c w_out[d][c]*codebook[idx[b][t]][c] + out_b[d]
__global__ __launch_bounds__(512) void zq_gemm(
    const float* __restrict__ cb, const float* __restrict__ w_outT,
    const float* __restrict__ out_bias, const int* __restrict__ idx,
    float* __restrict__ out) {
  __shared__ __align__(16) float At[32 * 64];
  __shared__ __align__(16) float Bt[32 * 256];
  __shared__ int idxs[256];
  int tid = threadIdx.x, tx = tid & 63, ty = tid >> 6;
  int t0 = blockIdx.x * 256, d0 = blockIdx.y * 64, b = blockIdx.z;
  if (tid < 256) idxs[tid] = idx[b * T_ + t0 + tid];
  __syncthreads();
  int t_l = tid & 255, kq = tid >> 8;
  int myidx = idxs[t_l];
  const float* myrow = cb + (size_t)myidx * CD_;
  float acc[8][4] = {};
  for (int kc = 0; kc < CD_; kc += 32) {
    __syncthreads();
    {
      int kk = tid >> 4, rq = tid & 15;
      *(float4*)&At[kk * 64 + rq * 4] =
          *(const float4*)&w_outT[(size_t)(kc + kk) * D_ + d0 + rq * 4];
    }
#pragma unroll
    for (int i = 0; i < 4; ++i) {
      int kg = kq * 4 + i;
      float4 v = *(const float4*)&myrow[kc + kg * 4];
      Bt[(kg * 4 + 0) * 256 + t_l] = v.x;
      Bt[(kg * 4 + 1) * 256 + t_l] = v.y;
      Bt[(kg * 4 + 2) * 256 + t_l] = v.z;
      Bt[(kg * 4 + 3) * 256 + t_l] = v.w;
    }
    __syncthreads();
#pragma unroll 8
    for (int kk = 0; kk < 32; ++kk) {
      float a[8], bv[4];
      *(float4*)&a[0] = *(const float4*)&At[kk * 64 + ty * 8];
      *(float4*)&a[4] = *(const float4*)&At[kk * 64 + ty * 8 + 4];
      *(float4*)&bv[0] = *(const float4*)&Bt[kk * 256 + tx * 4];
#pragma unroll
      for (int j = 0; j < 8; ++j)
#pragma unroll
        for (int m = 0; m < 4; ++m)
          acc[j][m] = fmaf(a[j], bv[m], acc[j][m]);
    }
  }
#pragma unroll
  for (int j = 0; j < 8; ++j) {
    int d = d0 + ty * 8 + j;
    float bias = out_bias[d];
    float4 o;
    o.x = acc[j][0] + bias; o.y = acc[j][1] + bias;
    o.z = acc[j][2] + bias; o.w = acc[j][3] + bias;
    *(float4*)&out[OUT_ZQ + (size_t)(b * D_ + d) * T_ + t0 + tx * 4] = o;
  }
}

extern "C" void kernel_launch(void* const* d_in, const int* in_sizes, int n_in,
                              void* d_out, int out_size, void* d_ws,
                              size_t ws_size, hipStream_t stream) {
  const float* z     = (const float*)d_in[0];
  const float* in_v  = (const float*)d_in[1];
  const float* in_g  = (const float*)d_in[2];
  const float* in_b  = (const float*)d_in[3];
  const float* out_v = (const float*)d_in[4];
  const float* out_g = (const float*)d_in[5];
  const float* out_b = (const float*)d_in[6];
  const float* cb    = (const float*)d_in[7];
  float* out = (float*)d_out;
  float* ws  = (float*)d_ws;

  unsigned short* zeN = (unsigned short*)(ws + WS_ZEN);
  unsigned short* cbb = (unsigned short*)(ws + WS_CBB);
  float* w_inT  = ws + WS_WINT;
  float* w_outT = ws + WS_WOUTT;
  float* c2     = ws + WS_C2;
  float* bestq  = ws + WS_BESTQ;
  int*   cnt    = (int*)(ws + WS_CNT);
  int*   cand   = (int*)(ws + WS_CAND);
  int*   idxw   = (int*)(ws + WS_IDX);

  prep_win<<<CD_, 256, 0, stream>>>(in_v, in_g, w_inT);
  prep_wout<<<D_, 256, 0, stream>>>(out_v, out_g, w_outT);
  prep_c2<<<CS_ / 4, 256, 0, stream>>>(cb, c2);
  cvt_cb<<<(CS_ * CD_ / 8) / 256, 256, 0, stream>>>(cb, cbb);

  ze_gemm<<<dim3(T_ / 256, CD_ / 64, B_), 512, 0, stream>>>(z, w_inT, in_b, out);
  ze_t<<<dim3(T_ / 64, CD_ / 64, B_), 256, 0, stream>>>(out + OUT_ZE, zeN);

  vq_scan<0><<<dim3(N_ / SCAN_ROWS, NSPLIT), 256, 0, stream>>>(
      zeN, cbb, c2, bestq, cnt, cand);
  vq_rowthr<<<N_ / 256, 256, 0, stream>>>(bestq);
  vq_scan<1><<<dim3(N_ / SCAN_ROWS, NSPLIT), 256, 0, stream>>>(
      zeN, cbb, c2, bestq, cnt, cand);
  vq_rescore<<<N_ / 64, 256, 0, stream>>>(out + OUT_ZE, cb, cnt, cand, out, idxw);

  zq_gemm<<<dim3(T_ / 256, D_ / 64, B_), 512, 0, stream>>>(cb, w_outT, out_b, idxw, out);
}

// Round 5
// 414.355 us; speedup vs baseline: 2.6889x; 1.2119x over previous
//
#include <hip/hip_runtime.h>
#include <math.h>

// Problem constants
#define B_  8
#define D_  1024
#define T_  2048
#define CD_ 256
#define CS_ 8192
#define N_  (B_*T_)

#define NSPLIT 8
#define CODES_PER_SPLIT (CS_/NSPLIT)   // 1024
#define DELTA 1.5f                     // score-units; >> 2*bf16 dot error

// scan geometry: 4 waves * 64 rows = 256 rows/block; 64-code LDS tiles
#define SCAN_WAVES 4
#define ROWS_PER_WAVE 64
#define SCAN_ROWS 256
#define TILE_CODES 64

// ws layout (float offsets). Total ~16 MB.
#define WS_ZEN   0                        // bf16 [N][256]   (2,097,152 float slots)
#define WS_CBB   2097152                  // bf16 [CS][256]  (1,048,576)
#define WS_WINT  (WS_CBB + 1048576)       // f32 [D][CD]
#define WS_WOB   (WS_WINT + D_*CD_)       // bf16 [D][CD] (131072 float slots)
#define WS_C2    (WS_WOB + D_*CD_/2)      // f32 [CS]
#define WS_BESTQ (WS_C2 + CS_)            // f32 [NSPLIT][N]; row 0 becomes thr
#define WS_CNT   (WS_BESTQ + NSPLIT*N_)   // int [N]
#define WS_CAND  (WS_CNT + N_)            // int [N][16]
#define WS_IDX   (WS_CAND + N_*16)        // int [N]

// d_out layout (floats): z_q, indices(as float), z_e
#define OUT_ZQ  0
#define OUT_IDX (B_*D_*T_)
#define OUT_ZE  (OUT_IDX + B_*T_)

using short8v = __attribute__((ext_vector_type(8))) short;
using float4v = __attribute__((ext_vector_type(4))) float;

__device__ __forceinline__ float wave_sum64(float v) {
#pragma unroll
  for (int off = 32; off >= 1; off >>= 1) v += __shfl_xor(v, off);
  return v;
}

__device__ __forceinline__ unsigned short f2bf_rne(float f) {
  unsigned int u = __float_as_uint(f);
  u += 0x7fffu + ((u >> 16) & 1u);
  return (unsigned short)(u >> 16);
}

__device__ __forceinline__ void gload_lds16(const void* g, void* l) {
  __builtin_amdgcn_global_load_lds(
      (const __attribute__((address_space(1))) void*)g,
      (__attribute__((address_space(3))) void*)l, 16, 0, 0);
}

// ---- prep: w_inT[d][c] = in_g[c] * in_v[c][d] / ||in_v[c,:]|| ----
__global__ void prep_win(const float* __restrict__ in_v,
                         const float* __restrict__ in_g,
                         float* __restrict__ w_inT) {
  int c = blockIdx.x, tid = threadIdx.x;  // 256 threads
  float v[4]; float s = 0.f;
#pragma unroll
  for (int i = 0; i < 4; ++i) {
    v[i] = in_v[c * D_ + tid + 256 * i];
    s = fmaf(v[i], v[i], s);
  }
  s = wave_sum64(s);
  __shared__ float sh[4];
  if ((tid & 63) == 0) sh[tid >> 6] = s;
  __syncthreads();
  float tot = sh[0] + sh[1] + sh[2] + sh[3];
  float scale = in_g[c] / sqrtf(tot);
#pragma unroll
  for (int i = 0; i < 4; ++i)
    w_inT[(tid + 256 * i) * CD_ + c] = v[i] * scale;
}

// ---- prep: wob[d][c] = bf16( out_g[d] * out_v[d][c] / ||out_v[d,:]|| ) ----
__global__ void prep_wout(const float* __restrict__ out_v,
                          const float* __restrict__ out_g,
                          unsigned short* __restrict__ wob) {
  int d = blockIdx.x, tid = threadIdx.x;  // 256 threads, c = tid
  float v = out_v[d * CD_ + tid];
  float s = wave_sum64(v * v);
  __shared__ float sh[4];
  if ((tid & 63) == 0) sh[tid >> 6] = s;
  __syncthreads();
  float tot = sh[0] + sh[1] + sh[2] + sh[3];
  float scale = out_g[d] / sqrtf(tot);
  wob[d * CD_ + tid] = f2bf_rne(v * scale);
}

// ---- prep: c2[s] = sum_c codebook[s][c]^2 ----
__global__ void prep_c2(const float* __restrict__ cb, float* __restrict__ c2) {
  int tid = threadIdx.x;  // 256 = 4 waves, one row per wave
  int w = tid >> 6, lane = tid & 63;
  int s = blockIdx.x * 4 + w;
  float acc = 0.f;
#pragma unroll
  for (int i = 0; i < 4; ++i) {
    float v = cb[(size_t)s * CD_ + lane + 64 * i];
    acc = fmaf(v, v, acc);
  }
  acc = wave_sum64(acc);
  if (lane == 0) c2[s] = acc;
}

// ---- prep: codebook fp32 -> bf16 row-major copy ----
__global__ void cvt_cb(const float* __restrict__ cb, unsigned short* __restrict__ cbb) {
  size_t i = (size_t)blockIdx.x * 256 + threadIdx.x;  // octet index
  float4 v0 = *(const float4*)&cb[i * 8];
  float4 v1 = *(const float4*)&cb[i * 8 + 4];
  float f[8] = {v0.x, v0.y, v0.z, v0.w, v1.x, v1.y, v1.z, v1.w};
  unsigned short us[8];
#pragma unroll
  for (int m = 0; m < 8; ++m) us[m] = f2bf_rne(f[m]);
  *(uint4*)&cbb[i * 8] = *(uint4*)&us[0];
}

// ---- K1: z_e[b][c][t] = sum_d w_in[c][d]*z[b][d][t] + in_b[c] ----
// tile 64c x 128t, TK=32, 256 threads, microtile 8c x 4t.
// Double-buffered global_load_lds staging: stage(next) issued before
// compute(cur); single barrier per K-tile drains it after compute.
__global__ __launch_bounds__(256) void ze_gemm(
    const float* __restrict__ z, const float* __restrict__ w_inT,
    const float* __restrict__ in_b, float* __restrict__ out) {
  __shared__ __align__(16) float At[2][32 * 64];    // 8KB each
  __shared__ __align__(16) float Bt[2][32 * 128];   // 16KB each
  int tid = threadIdx.x, tx = tid & 31, ty = tid >> 5;
  int w = tid >> 6, l = tid & 63;
  int t0 = blockIdx.x * 128, c0 = blockIdx.y * 64, b = blockIdx.z;
  const float* zb = z + (size_t)b * D_ * T_;

  auto stage = [&](int buf, int kc) {
    // At: 8 wave-calls of 1KB; call g covers rows kk=g*4..g*4+3 (lane = 4l floats)
#pragma unroll
    for (int i = 0; i < 2; ++i) {
      int g = w * 2 + i;
      int kk = g * 4 + (l >> 4);
      int c = (l & 15) * 4;
      gload_lds16(&w_inT[(size_t)(kc + kk) * CD_ + c0 + c], &At[buf][g * 256]);
    }
    // Bt: 16 wave-calls; call g covers rows kk=g*2..g*2+1
#pragma unroll
    for (int i = 0; i < 4; ++i) {
      int g = w * 4 + i;
      int kk = g * 2 + (l >> 5);
      int t = (l & 31) * 4;
      gload_lds16(&zb[(size_t)(kc + kk) * T_ + t0 + t], &Bt[buf][g * 256]);
    }
  };

  float acc[8][4] = {};
  stage(0, 0);
  __syncthreads();
  int cur = 0;
  for (int kt = 0; kt < D_ / 32; ++kt) {
    if (kt + 1 < D_ / 32) stage(cur ^ 1, (kt + 1) * 32);
#pragma unroll 8
    for (int kk = 0; kk < 32; ++kk) {
      float a[8], bv[4];
      *(float4*)&a[0] = *(const float4*)&At[cur][kk * 64 + ty * 8];
      *(float4*)&a[4] = *(const float4*)&At[cur][kk * 64 + ty * 8 + 4];
      *(float4*)&bv[0] = *(const float4*)&Bt[cur][kk * 128 + tx * 4];
#pragma unroll
      for (int j = 0; j < 8; ++j)
#pragma unroll
        for (int m = 0; m < 4; ++m)
          acc[j][m] = fmaf(a[j], bv[m], acc[j][m]);
    }
    __syncthreads();
    cur ^= 1;
  }
#pragma unroll
  for (int j = 0; j < 8; ++j) {
    int c = c0 + ty * 8 + j;
    float bias = in_b[c];
    float4 o;
    o.x = acc[j][0] + bias; o.y = acc[j][1] + bias;
    o.z = acc[j][2] + bias; o.w = acc[j][3] + bias;
    *(float4*)&out[OUT_ZE + (size_t)(b * CD_ + c) * T_ + t0 + tx * 4] = o;
  }
}

// ---- transpose+convert: z_e [b][c][t] f32 -> zeN [b*T+t][c] bf16 ----
__global__ __launch_bounds__(256) void ze_t(const float* __restrict__ ze,
                                            unsigned short* __restrict__ zeN) {
  __shared__ float tile[64][65];
  int t0 = blockIdx.x * 64, c0 = blockIdx.y * 64, b = blockIdx.z;
  int tid = threadIdx.x;
  int cr = tid >> 4, tq = tid & 15;
#pragma unroll
  for (int i = 0; i < 4; ++i) {
    int c = cr + 16 * i;
    float4 v = *(const float4*)&ze[((size_t)(b * CD_ + c0 + c)) * T_ + t0 + tq * 4];
    tile[c][tq * 4 + 0] = v.x; tile[c][tq * 4 + 1] = v.y;
    tile[c][tq * 4 + 2] = v.z; tile[c][tq * 4 + 3] = v.w;
  }
  __syncthreads();
  int tr = tid >> 2, qc = tid & 3;
  unsigned short us[16];
#pragma unroll
  for (int m = 0; m < 16; ++m) us[m] = f2bf_rne(tile[qc * 16 + m][tr]);
  size_t base = ((size_t)(b * T_ + t0 + tr)) * CD_ + c0 + qc * 16;
  *(uint4*)&zeN[base] = *(uint4*)&us[0];
  *(uint4*)&zeN[base + 8] = *(uint4*)&us[8];
}

// ---- K2: MFMA coarse scan, LDS-staged double-buffered (unchanged R4) ----
template <int COLLECT>
__global__ __launch_bounds__(256, 2) void vq_scan(
    const unsigned short* __restrict__ zeN, const unsigned short* __restrict__ cbb,
    const float* __restrict__ c2, float* __restrict__ bestq,
    int* __restrict__ cnt, int* __restrict__ cand) {
  __shared__ __align__(16) unsigned short smem[2][TILE_CODES * CD_];  // 2 x 32 KB
  int tid = threadIdx.x;
  int w = tid >> 6, l = tid & 63;
  int lrow = l & 15, lg = l >> 4;
  int rowbase = blockIdx.x * SCAN_ROWS + w * ROWS_PER_WAVE;
  int cq = blockIdx.y;
  int cbase0 = cq * CODES_PER_SPLIT;

  if (COLLECT == 0 && cq == 0)
    cnt[blockIdx.x * SCAN_ROWS + tid] = 0;

  short8v a[4][8];
#pragma unroll
  for (int rf = 0; rf < 4; ++rf)
#pragma unroll
    for (int ks = 0; ks < 8; ++ks)
      a[rf][ks] = *(const short8v*)&zeN[((size_t)(rowbase + rf * 16 + lrow)) * CD_ + ks * 32 + lg * 8];

  float best[16];
  float thr[16];
#pragma unroll
  for (int s = 0; s < 16; ++s) best[s] = -3.4e38f;
  if (COLLECT) {
#pragma unroll
    for (int s = 0; s < 16; ++s) {
      int rf = s >> 2, rg = s & 3;
      thr[s] = bestq[rowbase + rf * 16 + lg * 4 + rg];  // rowmax - DELTA
    }
  }

  int lhalf = l >> 5;
  int lcol = (l & 31) * 16;
  char* smem_b = (char*)&smem[0][0];
  const char* cbb_b = (const char*)cbb;
  int xsw = (lrow & 7) << 4;

  auto stage = [&](int buf, int cbase) {
#pragma unroll
    for (int r = 0; r < 8; ++r) {
      int code = w * 16 + r * 2 + lhalf;
      size_t goff = (size_t)(cbase + code) * 512 + (size_t)(lcol ^ ((code & 7) << 4));
      gload_lds16(cbb_b + goff, smem_b + buf * 32768 + (w * 8 + r) * 1024);
    }
  };

  stage(0, cbase0);
  __syncthreads();

  for (int t = 0; t < CODES_PER_SPLIT / TILE_CODES; ++t) {
    int buf = t & 1;
    int cbase = cbase0 + t * TILE_CODES;
    if (t + 1 < CODES_PER_SPLIT / TILE_CODES)
      stage(buf ^ 1, cbase + TILE_CODES);

    const char* bufb = smem_b + buf * 32768;
#pragma unroll
    for (int cf = 0; cf < 4; ++cf) {
      const char* bbase = bufb + (cf * 16 + lrow) * 512;
      float c2v = c2[cbase + cf * 16 + lrow];
      float4v acc[4];
#pragma unroll
      for (int rf = 0; rf < 4; ++rf) acc[rf] = (float4v){0.f, 0.f, 0.f, 0.f};
#pragma unroll
      for (int ks = 0; ks < 8; ++ks) {
        short8v bfrag = *(const short8v*)(bbase + ((ks * 64 + lg * 16) ^ xsw));
        acc[0] = __builtin_amdgcn_mfma_f32_16x16x32_bf16(a[0][ks], bfrag, acc[0], 0, 0, 0);
        acc[1] = __builtin_amdgcn_mfma_f32_16x16x32_bf16(a[1][ks], bfrag, acc[1], 0, 0, 0);
        acc[2] = __builtin_amdgcn_mfma_f32_16x16x32_bf16(a[2][ks], bfrag, acc[2], 0, 0, 0);
        acc[3] = __builtin_amdgcn_mfma_f32_16x16x32_bf16(a[3][ks], bfrag, acc[3], 0, 0, 0);
      }
      int ci = cbase + cf * 16 + lrow;
      float half_c2 = 0.5f * c2v;
#pragma unroll
      for (int rf = 0; rf < 4; ++rf)
#pragma unroll
        for (int rg = 0; rg < 4; ++rg) {
          float sc = acc[rf][rg] - half_c2;
          int slot = rf * 4 + rg;
          if (COLLECT) {
            if (sc >= thr[slot]) {
              int row = rowbase + rf * 16 + lg * 4 + rg;
              int pos = atomicAdd(&cnt[row], 1);
              if (pos < 16) cand[row * 16 + pos] = ci;
            }
          } else {
            best[slot] = fmaxf(best[slot], sc);
          }
        }
    }
    __syncthreads();
  }

  if (!COLLECT) {
#pragma unroll
    for (int s = 0; s < 16; ++s) {
      float v = best[s];
#pragma unroll
      for (int off = 1; off < 16; off <<= 1) v = fmaxf(v, __shfl_xor(v, off));
      best[s] = v;
    }
    if (lrow == 0) {
#pragma unroll
      for (int s = 0; s < 16; ++s) {
        int rf = s >> 2, rg = s & 3;
        bestq[cq * N_ + rowbase + rf * 16 + lg * 4 + rg] = best[s];
      }
    }
  }
}

// ---- fold split maxima into per-row threshold, in place (row 0 of bestq) ----
__global__ __launch_bounds__(256) void vq_rowthr(float* __restrict__ bestq) {
  int n = blockIdx.x * 256 + threadIdx.x;
  float m = bestq[n];
#pragma unroll
  for (int q = 1; q < NSPLIT; ++q) m = fmaxf(m, bestq[q * N_ + n]);
  bestq[n] = m - DELTA;
}

// ---- exact fp32 rescore of candidates; lexicographic (dist, idx) min ----
__global__ __launch_bounds__(256) void vq_rescore(
    const float* __restrict__ ze, const float* __restrict__ cb,
    const int* __restrict__ cnt, const int* __restrict__ cand,
    float* __restrict__ out, int* __restrict__ idx_ws) {
  int tid = threadIdx.x;
  int n = blockIdx.x * 64 + (tid >> 2);
  int j = tid & 3;
  int b = n >> 11, t = n & (T_ - 1);
  const float* zr = ze + ((size_t)b * CD_) * T_ + t;  // element k at zr[k*T_]
  int m = cnt[n]; if (m > 16) m = 16;
  float bd = 3.4e38f; int bi = 0x7fffffff;
  for (int i = 0; i < m; ++i) {
    int c = cand[n * 16 + i];
    const float* cr = cb + (size_t)c * CD_;
    float d = 0.f;
    for (int k = j; k < CD_; k += 4) {
      float diff = zr[(size_t)k * T_] - cr[k];
      d = fmaf(diff, diff, d);
    }
    d += __shfl_xor(d, 1);
    d += __shfl_xor(d, 2);
    if (d < bd || (d == bd && c < bi)) { bd = d; bi = c; }
  }
  if (j == 0) {
    idx_ws[n] = bi;
    out[OUT_IDX + n] = (float)bi;
  }
}

// ---- K3 (MFMA): z_q[b][d][t] = sum_c wob[d][c]*cbb[idx[b][t]][c] + out_b[d]
// block: 256 thr = 4 waves x 64 d-rows (A register-resident), 64 t-cols.
// B = gathered codebook rows staged via per-lane-source global_load_lds,
// XOR-swizzled like vq_scan. K=256 in one staged tile.
__global__ __launch_bounds__(256, 2) void zq_mfma(
    const unsigned short* __restrict__ wob, const unsigned short* __restrict__ cbb,
    const float* __restrict__ out_bias, const int* __restrict__ idx,
    float* __restrict__ out) {
  __shared__ __align__(16) unsigned short Bs[64 * CD_];  // 32 KB
  __shared__ int idxs[64];
  int tid = threadIdx.x;
  int w = tid >> 6, l = tid & 63;
  int lrow = l & 15, lg = l >> 4;
  int t0 = blockIdx.x * 64, d0 = blockIdx.y * 256, b = blockIdx.z;
  int rowbase = d0 + w * 64;

  if (tid < 64) idxs[tid] = idx[b * T_ + t0 + tid];

  // A fragments: 4 rf x 8 ks (w_out rows, k=c contiguous)
  short8v a[4][8];
#pragma unroll
  for (int rf = 0; rf < 4; ++rf)
#pragma unroll
    for (int ks = 0; ks < 8; ++ks)
      a[rf][ks] = *(const short8v*)&wob[((size_t)(rowbase + rf * 16 + lrow)) * CD_ + ks * 32 + lg * 8];

  __syncthreads();  // idxs ready

  int lhalf = l >> 5;
  int lcol = (l & 31) * 16;
  char* Bs_b = (char*)&Bs[0];
  const char* cbb_b = (const char*)cbb;
#pragma unroll
  for (int r = 0; r < 8; ++r) {
    int t = w * 16 + r * 2 + lhalf;
    int row = idxs[t];
    size_t goff = (size_t)row * 512 + (size_t)(lcol ^ ((t & 7) << 4));
    gload_lds16(cbb_b + goff, Bs_b + (w * 8 + r) * 1024);
  }
  __syncthreads();  // drains vmcnt

  int xsw = (lrow & 7) << 4;
  float4v acc[4][4];
#pragma unroll
  for (int rf = 0; rf < 4; ++rf)
#pragma unroll
    for (int cf = 0; cf < 4; ++cf) acc[rf][cf] = (float4v){0.f, 0.f, 0.f, 0.f};
#pragma unroll
  for (int cf = 0; cf < 4; ++cf) {
    const char* bbase = Bs_b + (cf * 16 + lrow) * 512;
#pragma unroll
    for (int ks = 0; ks < 8; ++ks) {
      short8v bfrag = *(const short8v*)(bbase + ((ks * 64 + lg * 16) ^ xsw));
      acc[0][cf] = __builtin_amdgcn_mfma_f32_16x16x32_bf16(a[0][ks], bfrag, acc[0][cf], 0, 0, 0);
      acc[1][cf] = __builtin_amdgcn_mfma_f32_16x16x32_bf16(a[1][ks], bfrag, acc[1][cf], 0, 0, 0);
      acc[2][cf] = __builtin_amdgcn_mfma_f32_16x16x32_bf16(a[2][ks], bfrag, acc[2][cf], 0, 0, 0);
      acc[3][cf] = __builtin_amdgcn_mfma_f32_16x16x32_bf16(a[3][ks], bfrag, acc[3][cf], 0, 0, 0);
    }
  }
#pragma unroll
  for (int rf = 0; rf < 4; ++rf) {
    float bias[4];
#pragma unroll
    for (int rg = 0; rg < 4; ++rg) bias[rg] = out_bias[rowbase + rf * 16 + lg * 4 + rg];
#pragma unroll
    for (int cf = 0; cf < 4; ++cf) {
      int t = t0 + cf * 16 + lrow;
#pragma unroll
      for (int rg = 0; rg < 4; ++rg) {
        int d = rowbase + rf * 16 + lg * 4 + rg;
        out[OUT_ZQ + (size_t)(b * D_ + d) * T_ + t] = acc[rf][cf][rg] + bias[rg];
      }
    }
  }
}

extern "C" void kernel_launch(void* const* d_in, const int* in_sizes, int n_in,
                              void* d_out, int out_size, void* d_ws,
                              size_t ws_size, hipStream_t stream) {
  const float* z     = (const float*)d_in[0];
  const float* in_v  = (const float*)d_in[1];
  const float* in_g  = (const float*)d_in[2];
  const float* in_b  = (const float*)d_in[3];
  const float* out_v = (const float*)d_in[4];
  const float* out_g = (const float*)d_in[5];
  const float* out_b = (const float*)d_in[6];
  const float* cb    = (const float*)d_in[7];
  float* out = (float*)d_out;
  float* ws  = (float*)d_ws;

  unsigned short* zeN = (unsigned short*)(ws + WS_ZEN);
  unsigned short* cbb = (unsigned short*)(ws + WS_CBB);
  float* w_inT  = ws + WS_WINT;
  unsigned short* wob = (unsigned short*)(ws + WS_WOB);
  float* c2     = ws + WS_C2;
  float* bestq  = ws + WS_BESTQ;
  int*   cnt    = (int*)(ws + WS_CNT);
  int*   cand   = (int*)(ws + WS_CAND);
  int*   idxw   = (int*)(ws + WS_IDX);

  prep_win<<<CD_, 256, 0, stream>>>(in_v, in_g, w_inT);
  prep_wout<<<D_, 256, 0, stream>>>(out_v, out_g, wob);
  prep_c2<<<CS_ / 4, 256, 0, stream>>>(cb, c2);
  cvt_cb<<<(CS_ * CD_ / 8) / 256, 256, 0, stream>>>(cb, cbb);

  ze_gemm<<<dim3(T_ / 128, CD_ / 64, B_), 256, 0, stream>>>(z, w_inT, in_b, out);
  ze_t<<<dim3(T_ / 64, CD_ / 64, B_), 256, 0, stream>>>(out + OUT_ZE, zeN);

  vq_scan<0><<<dim3(N_ / SCAN_ROWS, NSPLIT), 256, 0, stream>>>(
      zeN, cbb, c2, bestq, cnt, cand);
  vq_rowthr<<<N_ / 256, 256, 0, stream>>>(bestq);
  vq_scan<1><<<dim3(N_ / SCAN_ROWS, NSPLIT), 256, 0, stream>>>(
      zeN, cbb, c2, bestq, cnt, cand);
  vq_rescore<<<N_ / 64, 256, 0, stream>>>(out + OUT_ZE, cb, cnt, cand, out, idxw);

  zq_mfma<<<dim3(T_ / 64, D_ / 256, B_), 256, 0, stream>>>(wob, cbb, out_b, idxw, out);
}